// Round 8
// baseline (2195.541 us; speedup 1.0000x reference)
//
#include <hip/hip_runtime.h>
#include <stdint.h>

// KGEdges round 8 — FP32-OUTPUT hypothesis (S2), zero workspace.
// Post-mortem chain: R1 NaN => float inputs are fp32. R4==R6 bit-match (blind
// dict vs size-checked slots) => slot order is dict order. No 1e8 artifacts =>
// mask int32. Six function variants (literal / transposed / W-T) all decorrelate
// from ref at exactly max|ref| + |N(0,sigma_ref)| => the FUNCTION is right and the
// OUTPUT ENCODING is wrong: the harness label "(bf16" is a hardcoded f-string
// (zero dtype info), and max|ref|=3.296875 bf16-exact is explained by the harness
// quantizing the REFERENCE for comparison. Writing u16 bf16 pairs into an fp32
// buffer makes word k ~= score[2k+1]: deterministic, decorrelated, sigma-matched —
// reproducing R2..R7 exactly (incl. bit-exact pairs). Fix: write fp32.
// Function (literal reference): out[b,i,j] = sum_d w_out[d]*tanh(head[b,j,d] +
// child[b,i,d]) + mm_i + mm_j ; head = enc@Wh^T + bh, child = enc@Wc^T.

typedef __attribute__((ext_vector_type(4))) float f32x4;

#define SL 256
#define ENC 1024
#define ED 256
#define HSTR 264  // u16 row stride for head/child LDS (528 B)

__device__ __forceinline__ unsigned short f32_to_bf16_rne(float f) {
  uint32_t u = __float_as_uint(f);
  return (unsigned short)((u + 0x7FFFu + ((u >> 16) & 1u)) >> 16);
}
__device__ __forceinline__ float bfu(unsigned short h) {
  return __uint_as_float(((uint32_t)h) << 16);
}

__global__ __launch_bounds__(256)
void kgedges_f32out(const float* __restrict__ enc, const int* __restrict__ mask,
                    const float* __restrict__ Wh, const float* __restrict__ Wc,
                    const float* __restrict__ p3, const float* __restrict__ p5,
                    float* __restrict__ out) {
  __shared__ float Wt[64 * 64];                // 16 KB  W tile: 64 d-rows x 64 k
  __shared__ float Et[32 * 64];                //  8 KB  enc tile: 32 rows x 64 k
  __shared__ unsigned short headS[32 * HSTR];  // 16.5 KB bf16
  __shared__ unsigned short childS[32 * HSTR]; // 16.5 KB bf16
  __shared__ float red[256];
  __shared__ float bhS[256];
  __shared__ float wS[256];                    // total ~60 KB

  const int t = threadIdx.x;
  const int j0 = blockIdx.x * 32, i0 = blockIdx.y * 32, b = blockIdx.z;

  // ---- bh vs w_out by energy (protective; dict order confirmed by R4==R6) ----
  float va = p3[t], vb = p5[t];
  red[t] = va * va;
  __syncthreads();
  for (int s = 128; s > 0; s >>= 1) { if (t < s) red[t] += red[t + s]; __syncthreads(); }
  const float sa = red[0];
  __syncthreads();
  red[t] = vb * vb;
  __syncthreads();
  for (int s = 128; s > 0; s >>= 1) { if (t < s) red[t] += red[t + s]; __syncthreads(); }
  const float sb = red[0];
  __syncthreads();
  const bool dictOrder = (sa <= sb);  // lower energy = bh (var 1/1024 vs 1/256)
  bhS[t] = dictOrder ? va : vb;
  wS[t] = dictOrder ? vb : va;

  const int g = t >> 3;   // row 0..31 within tile
  const int e = t & 7;    // d-phase 0..7 (thread owns d = d0 + e + 8m)

  // ---- projections: ph=0 head (j-rows, Wh, +bh); ph=1 child (i-rows, Wc) ----
  for (int ph = 0; ph < 2; ++ph) {
    const float* Wsrc = ph ? Wc : Wh;
    const int rbase = b * SL + (ph ? i0 : j0);
    unsigned short* dst = ph ? childS : headS;
    for (int d0 = 0; d0 < ED; d0 += 64) {
      float acc[8] = {0.f, 0.f, 0.f, 0.f, 0.f, 0.f, 0.f, 0.f};
      for (int k0 = 0; k0 < ENC; k0 += 64) {
        __syncthreads();  // previous tile's LDS reads complete
#pragma unroll
        for (int p = 0; p < 4; ++p) {  // Wt: rows d0..d0+63, cols k0..k0+63
          int u = t + 256 * p;
          int r = u >> 4, c4 = (u & 15) << 2;
          *(f32x4*)&Wt[r * 64 + c4] =
              *(const f32x4*)&Wsrc[(size_t)(d0 + r) * ENC + k0 + c4];
        }
#pragma unroll
        for (int p = 0; p < 2; ++p) {  // Et: rows rbase..rbase+31
          int u = t + 256 * p;
          int r = u >> 4, c4 = (u & 15) << 2;
          *(f32x4*)&Et[r * 64 + c4] =
              *(const f32x4*)&enc[(size_t)(rbase + r) * ENC + k0 + c4];
        }
        __syncthreads();  // publish tiles
        for (int k4 = 0; k4 < 64; k4 += 4) {
          f32x4 ev = *(const f32x4*)&Et[g * 64 + k4];
#pragma unroll
          for (int m = 0; m < 8; ++m) {
            f32x4 wv = *(const f32x4*)&Wt[(e + 8 * m) * 64 + k4];
            acc[m] = fmaf(ev[0], wv[0], acc[m]);
            acc[m] = fmaf(ev[1], wv[1], acc[m]);
            acc[m] = fmaf(ev[2], wv[2], acc[m]);
            acc[m] = fmaf(ev[3], wv[3], acc[m]);
          }
        }
      }
#pragma unroll
      for (int m = 0; m < 8; ++m) {  // flush this d-tile (bias only on head)
        int d = d0 + e + 8 * m;
        float v = acc[m] + (ph == 0 ? bhS[d] : 0.0f);
        dst[g * HSTR + d] = f32_to_bf16_rne(v);
      }
    }
  }
  __syncthreads();  // publish headS/childS

  // ---- pairwise epilogue: head pairs with COLUMN j, child with ROW i ----
#pragma unroll
  for (int rep = 0; rep < 4; ++rep) {
    int idx = t + 256 * rep;
    int ii = idx >> 5, jj = idx & 31;
    float a = 0.f;
    for (int d = 0; d < ED; ++d) {
      float hv = bfu(headS[jj * HSTR + d]);
      float cv = bfu(childS[ii * HSTR + d]);
      a = fmaf(wS[d], tanhf(hv + cv), a);
    }
    int gi = b * SL + i0 + ii;
    int gj = j0 + jj;
    float mi = (1.0f - (float)mask[gi]) * -1.0e8f;
    float mj = (1.0f - (float)mask[b * SL + gj]) * -1.0e8f;
    out[(size_t)gi * SL + gj] = a + mi + mj;   // <-- FP32 OUTPUT (the round-8 fix)
  }
}

extern "C" void kernel_launch(void* const* d_in, const int* in_sizes, int n_in,
                              void* d_out, int out_size, void* d_ws, size_t ws_size,
                              hipStream_t stream) {
  (void)d_ws; (void)ws_size; (void)out_size;
  int ienc = 0, imask = 1, iw1 = 2, ib1 = 3, iw2 = 4, ib2 = 5;
  if (n_in == 6 && in_sizes) {
    const int want[6] = {2097152, 2048, 262144, 256, 262144, 256};
    bool ok = true;
    for (int i = 0; i < 6; ++i) ok = ok && (in_sizes[i] == want[i]);
    if (!ok) {
      int ws[2], bs[2], nw = 0, nb = 0, en = -1, mk = -1;
      for (int i = 0; i < 6; ++i) {
        if (in_sizes[i] == 2097152) en = i;
        else if (in_sizes[i] == 2048) mk = i;
        else if (in_sizes[i] == 262144 && nw < 2) ws[nw++] = i;
        else if (in_sizes[i] == 256 && nb < 2) bs[nb++] = i;
      }
      if (en >= 0 && mk >= 0 && nw == 2 && nb == 2) {
        ienc = en; imask = mk; iw1 = ws[0]; iw2 = ws[1]; ib1 = bs[0]; ib2 = bs[1];
      }
    }
  }
  kgedges_f32out<<<dim3(8, 8, 8), 256, 0, stream>>>(
      (const float*)d_in[ienc], (const int*)d_in[imask],
      (const float*)d_in[iw1], (const float*)d_in[iw2],
      (const float*)d_in[ib1], (const float*)d_in[ib2],
      (float*)d_out);
}

// Round 9
// 115.943 us; speedup vs baseline: 18.9364x; 18.9364x over previous
//
#include <hip/hip_runtime.h>
#include <hip/hip_bf16.h>
#include <stdint.h>

// KGEdges round 9 — resurrect the bit-proven R2 MFMA pipeline with fp32 output.
// Semantics (proven green in R8): out[b,i,j] = sum_d w_out[d]*tanh(head[b,j,d]
// + child[b,i,d]) + mm_i + mm_j ; head = enc@Wh^T + bh, child = enc@Wc^T.
// Inputs fp32 (R1 NaN proof), mask int32, OUTPUT FP32 (R8 proof). Slots dict-order
// (R4==R6 bit-proof). ws_size >= 9.2 MiB (R2==R4 bit-proof). tanh identity:
// sum w*tanh(x) = S + sum(-2w)*rcp(exp2(Kx_h+Kx_c)+1), K=2*log2(e).
// Fallback to the R8 green kernel if ws_size is unexpectedly small.

typedef __bf16 bf16_t;
typedef __attribute__((ext_vector_type(8))) __bf16 bf16x8;
typedef __attribute__((ext_vector_type(4))) float f32x4;

#define SL 256
#define ENC 1024
#define NTOT 512
#define N_ENC 2097152   // 8*256*1024
#define N_W 262144      // 256*1024
#define KSCALE 2.8853900817779268f  // 2*log2(e)

__device__ __forceinline__ void async16(void* lds, const void* g) {
  __builtin_amdgcn_global_load_lds(
      (const __attribute__((address_space(1))) uint32_t*)g,
      (__attribute__((address_space(3))) uint32_t*)lds, 16, 0, 0);
}
__device__ __forceinline__ unsigned short f32_to_bf16_rne(float f) {
  uint32_t u = __float_as_uint(f);
  return (unsigned short)((u + 0x7FFFu + ((u >> 16) & 1u)) >> 16);
}
__device__ __forceinline__ float bfu(unsigned short h) {
  return __uint_as_float(((uint32_t)h) << 16);
}

// ---- convert: bf16 copies of enc, Wh, Wc (WB = [Wh;Wc] rows 0..511) ----
__global__ __launch_bounds__(256)
void convert_kernel(const float* __restrict__ enc, const float* __restrict__ Wh,
                    const float* __restrict__ Wc,
                    unsigned short* __restrict__ encB, unsigned short* __restrict__ WB) {
  int gi = (blockIdx.x * 256 + threadIdx.x) * 4;
  const float* src;
  unsigned short* dst;
  int off;
  if (gi < N_ENC) {
    src = enc; off = gi; dst = encB + gi;
  } else if (gi < N_ENC + N_W) {
    src = Wh; off = gi - N_ENC; dst = WB + off;
  } else {
    src = Wc; off = gi - N_ENC - N_W; dst = WB + N_W + off;
  }
  f32x4 v = *(const f32x4*)(src + off);
  ushort4 o;
  o.x = f32_to_bf16_rne(v[0]); o.y = f32_to_bf16_rne(v[1]);
  o.z = f32_to_bf16_rne(v[2]); o.w = f32_to_bf16_rne(v[3]);
  *(ushort4*)dst = o;
}

// ---- prep: bhF, w2F=-2w, Ssum=sum w, minus-mask mmF[2048] ----
__global__ void prep_kernel(const float* __restrict__ bh, const float* __restrict__ wout,
                            const int* __restrict__ mask,
                            float* __restrict__ bhF, float* __restrict__ w2F,
                            float* __restrict__ Ssum, float* __restrict__ mmF) {
  int t = threadIdx.x;
  bhF[t] = bh[t];
  float w = wout[t];
  w2F[t] = -2.0f * w;
  __shared__ float red[256];
  red[t] = w;
  __syncthreads();
  for (int s = 128; s > 0; s >>= 1) {
    if (t < s) red[t] += red[t + s];
    __syncthreads();
  }
  if (t == 0) Ssum[0] = red[0];
  for (int s = t; s < 2048; s += 256)
    mmF[s] = (1.0f - (float)mask[s]) * -1.0e8f;
}

// ---- proj: hc[s][0:256]=K*(enc@Wh^T+bh) [head], hc[s][256:512]=K*(enc@Wc^T) ----
// 64x64 tile, BK=32, 4 waves each 2x2 MFMA 16x16x32 bf16. Bit-proven in R2.
__global__ __launch_bounds__(256)
void proj_kernel(const unsigned short* __restrict__ A, const unsigned short* __restrict__ WB,
                 const float* __restrict__ bhF, float* __restrict__ hc) {
  __shared__ bf16_t As[64 * 32];
  __shared__ bf16_t Bs[64 * 32];
  const int t = threadIdx.x;
  const int wv = t >> 6, lane = t & 63;
  const int m0 = blockIdx.x * 64;   // 32 blocks (2048 rows)
  const int n0 = blockIdx.y * 64;   // 8 blocks (512 cols of [head|child])
  const int srow = t >> 2, schunk = t & 3;
  const int mq = (wv & 1) * 32, nq = (wv >> 1) * 32;
  const int fr = lane & 15, kq = lane >> 4;

  f32x4 acc00 = {0.f, 0.f, 0.f, 0.f};
  f32x4 acc01 = acc00, acc10 = acc00, acc11 = acc00;

  const unsigned short* gA = A + (size_t)(m0 + srow) * ENC + schunk * 8;
  const unsigned short* gB = WB + (size_t)(n0 + srow) * ENC + schunk * 8;

  for (int k0 = 0; k0 < ENC; k0 += 32) {
    __syncthreads();
    async16(&As[wv * 512], gA + k0);  // wave-uniform LDS base + lane*16B
    async16(&Bs[wv * 512], gB + k0);
    __syncthreads();
    bf16x8 a0 = *(const bf16x8*)&As[(mq + fr) * 32 + kq * 8];
    bf16x8 a1 = *(const bf16x8*)&As[(mq + 16 + fr) * 32 + kq * 8];
    bf16x8 b0 = *(const bf16x8*)&Bs[(nq + fr) * 32 + kq * 8];
    bf16x8 b1 = *(const bf16x8*)&Bs[(nq + 16 + fr) * 32 + kq * 8];
    acc00 = __builtin_amdgcn_mfma_f32_16x16x32_bf16(a0, b0, acc00, 0, 0, 0);
    acc01 = __builtin_amdgcn_mfma_f32_16x16x32_bf16(a0, b1, acc01, 0, 0, 0);
    acc10 = __builtin_amdgcn_mfma_f32_16x16x32_bf16(a1, b0, acc10, 0, 0, 0);
    acc11 = __builtin_amdgcn_mfma_f32_16x16x32_bf16(a1, b1, acc11, 0, 0, 0);
  }
  // C/D: col=lane&15, row=(lane>>4)*4+r
  const int colA = n0 + nq + fr;
  const int colB = colA + 16;
  const float biasA = (colA < 256) ? bhF[colA] : 0.0f;
  const float biasB = (colB < 256) ? bhF[colB] : 0.0f;
#pragma unroll
  for (int r = 0; r < 4; ++r) {
    int row0 = m0 + mq + kq * 4 + r;
    int row1 = row0 + 16;
    hc[(size_t)row0 * NTOT + colA] = KSCALE * (acc00[r] + biasA);
    hc[(size_t)row0 * NTOT + colB] = KSCALE * (acc01[r] + biasB);
    hc[(size_t)row1 * NTOT + colA] = KSCALE * (acc10[r] + biasA);
    hc[(size_t)row1 * NTOT + colB] = KSCALE * (acc11[r] + biasB);
  }
}

// ---- edge: out[b,i,j] = S + sum_d w2[d]*rcp(exp2(h'[j,d]+c'[i,d])+1) + mm_i + mm_j ----
// 32x32 (i,j) tile; thread 2x2 micro-tile at (+16,+16). head pairs with COLUMN j.
// LDS stride 260 f32: frag reads <=2-way bank aliasing (free per m136).
#define LSTR 260
__global__ __launch_bounds__(256)
void edge_kernel(const float* __restrict__ hc, const float* __restrict__ w2,
                 const float* __restrict__ Ssum, const float* __restrict__ mmF,
                 float* __restrict__ out) {
  __shared__ float ldH[32 * LSTR];
  __shared__ float ldC[32 * LSTR];
  const int t = threadIdx.x;
  const int b = blockIdx.z;
  const int i0 = blockIdx.y * 32;
  const int j0 = blockIdx.x * 32;
  const int sbase = b * SL;

  for (int u = t; u < 32 * 64; u += 256) {
    int row = u >> 6;
    int c4 = (u & 63) << 2;
    f32x4 hv = *(const f32x4*)&hc[(size_t)(sbase + j0 + row) * NTOT + c4];        // head(j)
    f32x4 cv = *(const f32x4*)&hc[(size_t)(sbase + i0 + row) * NTOT + 256 + c4];  // child(i)
    *(f32x4*)&ldH[row * LSTR + c4] = hv;
    *(f32x4*)&ldC[row * LSTR + c4] = cv;
  }
  __syncthreads();

  const float S = Ssum[0];
  const int tx = t & 15, ty = t >> 4;
  const float* hp0 = &ldH[tx * LSTR];
  const float* hp1 = &ldH[(tx + 16) * LSTR];
  const float* cp0 = &ldC[ty * LSTR];
  const float* cp1 = &ldC[(ty + 16) * LSTR];
  float a00 = 0.f, a01 = 0.f, a10 = 0.f, a11 = 0.f;

#pragma unroll 8
  for (int d = 0; d < 256; d += 4) {
    f32x4 h0 = *(const f32x4*)&hp0[d];
    f32x4 h1 = *(const f32x4*)&hp1[d];
    f32x4 c0 = *(const f32x4*)&cp0[d];
    f32x4 c1 = *(const f32x4*)&cp1[d];
    f32x4 w4 = *(const f32x4*)&w2[d];  // wave-uniform
#pragma unroll
    for (int e = 0; e < 4; ++e) {
      float he0 = h0[e], he1 = h1[e], ce0 = c0[e], ce1 = c1[e], we = w4[e];
      float r00 = __builtin_amdgcn_rcpf(__builtin_amdgcn_exp2f(ce0 + he0) + 1.0f);
      float r01 = __builtin_amdgcn_rcpf(__builtin_amdgcn_exp2f(ce0 + he1) + 1.0f);
      float r10 = __builtin_amdgcn_rcpf(__builtin_amdgcn_exp2f(ce1 + he0) + 1.0f);
      float r11 = __builtin_amdgcn_rcpf(__builtin_amdgcn_exp2f(ce1 + he1) + 1.0f);
      a00 = fmaf(we, r00, a00);
      a01 = fmaf(we, r01, a01);
      a10 = fmaf(we, r10, a10);
      a11 = fmaf(we, r11, a11);
    }
  }

  const int gi0 = sbase + i0 + ty, gi1 = gi0 + 16;   // out rows (i)
  const int gj0 = j0 + tx, gj1 = gj0 + 16;           // out cols (j)
  const float mi0 = mmF[gi0], mi1 = mmF[gi1];
  const float mj0 = mmF[sbase + gj0], mj1 = mmF[sbase + gj1];
  out[(size_t)gi0 * SL + gj0] = S + a00 + mi0 + mj0;
  out[(size_t)gi0 * SL + gj1] = S + a01 + mi0 + mj1;
  out[(size_t)gi1 * SL + gj0] = S + a10 + mi1 + mj0;
  out[(size_t)gi1 * SL + gj1] = S + a11 + mi1 + mj1;
}

// ================= Fallback: R8's green fused kernel (verbatim) =================
#define ED 256
#define HSTR 264
__global__ __launch_bounds__(256)
void kgedges_f32out(const float* __restrict__ enc, const int* __restrict__ mask,
                    const float* __restrict__ Wh, const float* __restrict__ Wc,
                    const float* __restrict__ p3, const float* __restrict__ p5,
                    float* __restrict__ out) {
  __shared__ float Wt[64 * 64];
  __shared__ float Et[32 * 64];
  __shared__ unsigned short headS[32 * HSTR];
  __shared__ unsigned short childS[32 * HSTR];
  __shared__ float red[256];
  __shared__ float bhS[256];
  __shared__ float wS[256];
  const int t = threadIdx.x;
  const int j0 = blockIdx.x * 32, i0 = blockIdx.y * 32, b = blockIdx.z;
  float va = p3[t], vb = p5[t];
  red[t] = va * va;
  __syncthreads();
  for (int s = 128; s > 0; s >>= 1) { if (t < s) red[t] += red[t + s]; __syncthreads(); }
  const float sa = red[0];
  __syncthreads();
  red[t] = vb * vb;
  __syncthreads();
  for (int s = 128; s > 0; s >>= 1) { if (t < s) red[t] += red[t + s]; __syncthreads(); }
  const float sb = red[0];
  __syncthreads();
  const bool dictOrder = (sa <= sb);
  bhS[t] = dictOrder ? va : vb;
  wS[t] = dictOrder ? vb : va;
  const int g = t >> 3;
  const int e = t & 7;
  for (int ph = 0; ph < 2; ++ph) {
    const float* Wsrc = ph ? Wc : Wh;
    const int rbase = b * SL + (ph ? i0 : j0);
    unsigned short* dst = ph ? childS : headS;
    for (int d0 = 0; d0 < ED; d0 += 64) {
      float acc[8] = {0.f, 0.f, 0.f, 0.f, 0.f, 0.f, 0.f, 0.f};
      for (int k0 = 0; k0 < ENC; k0 += 64) {
        __syncthreads();
#pragma unroll
        for (int p = 0; p < 4; ++p) {
          int u = t + 256 * p;
          int r = u >> 4, c4 = (u & 15) << 2;
          *(f32x4*)&Wt[r * 64 + c4] =
              *(const f32x4*)&Wsrc[(size_t)(d0 + r) * ENC + k0 + c4];
        }
#pragma unroll
        for (int p = 0; p < 2; ++p) {
          int u = t + 256 * p;
          int r = u >> 4, c4 = (u & 15) << 2;
          *(f32x4*)&Et[r * 64 + c4] =
              *(const f32x4*)&enc[(size_t)(rbase + r) * ENC + k0 + c4];
        }
        __syncthreads();
        for (int k4 = 0; k4 < 64; k4 += 4) {
          f32x4 ev = *(const f32x4*)&Et[g * 64 + k4];
#pragma unroll
          for (int m = 0; m < 8; ++m) {
            f32x4 wv = *(const f32x4*)&Wt[(e + 8 * m) * 64 + k4];
            acc[m] = fmaf(ev[0], wv[0], acc[m]);
            acc[m] = fmaf(ev[1], wv[1], acc[m]);
            acc[m] = fmaf(ev[2], wv[2], acc[m]);
            acc[m] = fmaf(ev[3], wv[3], acc[m]);
          }
        }
      }
#pragma unroll
      for (int m = 0; m < 8; ++m) {
        int d = d0 + e + 8 * m;
        float v = acc[m] + (ph == 0 ? bhS[d] : 0.0f);
        dst[g * HSTR + d] = f32_to_bf16_rne(v);
      }
    }
  }
  __syncthreads();
#pragma unroll
  for (int rep = 0; rep < 4; ++rep) {
    int idx = t + 256 * rep;
    int ii = idx >> 5, jj = idx & 31;
    float a = 0.f;
    for (int d = 0; d < ED; ++d) {
      float hv = bfu(headS[jj * HSTR + d]);
      float cv = bfu(childS[ii * HSTR + d]);
      a = fmaf(wS[d], tanhf(hv + cv), a);
    }
    int gi = b * SL + i0 + ii;
    int gj = j0 + jj;
    float mi = (1.0f - (float)mask[gi]) * -1.0e8f;
    float mj = (1.0f - (float)mask[b * SL + gj]) * -1.0e8f;
    out[(size_t)gi * SL + gj] = a + mi + mj;
  }
}

extern "C" void kernel_launch(void* const* d_in, const int* in_sizes, int n_in,
                              void* d_out, int out_size, void* d_ws, size_t ws_size,
                              hipStream_t stream) {
  (void)in_sizes; (void)n_in; (void)out_size;
  const float* enc = (const float*)d_in[0];   // (8,256,1024) fp32
  const int* mask = (const int*)d_in[1];      // (8,256) int32
  const float* Wh = (const float*)d_in[2];    // (256,1024) fp32
  const float* bh = (const float*)d_in[3];    // (256,) fp32
  const float* Wc = (const float*)d_in[4];    // (256,1024) fp32
  const float* wout = (const float*)d_in[5];  // (256,) fp32
  float* out = (float*)d_out;

  // ws layout (~9.3 MiB, bit-proven valid in R2)
  const size_t NEED = (size_t)(9u << 20) + (512u << 10);
  if (ws_size >= NEED) {
    char* W = (char*)d_ws;
    float* hc = (float*)W;                                   // 4 MiB (2048x512 f32)
    unsigned short* encB = (unsigned short*)(W + (4 << 20)); // 4 MiB
    unsigned short* WB = (unsigned short*)(W + (8 << 20));   // 1 MiB ([Wh;Wc])
    float* bhF = (float*)(W + (9 << 20));
    float* w2F = bhF + 256;
    float* Ssum = w2F + 256;
    float* mmF = Ssum + 16;  // 2048 f32
    convert_kernel<<<2560, 256, 0, stream>>>(enc, Wh, Wc, encB, WB);
    prep_kernel<<<1, 256, 0, stream>>>(bh, wout, mask, bhF, w2F, Ssum, mmF);
    proj_kernel<<<dim3(32, 8), 256, 0, stream>>>(encB, WB, bhF, hc);
    edge_kernel<<<dim3(8, 8, 8), 256, 0, stream>>>(hc, w2F, Ssum, mmF, out);
  } else {
    kgedges_f32out<<<dim3(8, 8, 8), 256, 0, stream>>>(enc, mask, Wh, Wc, bh, wout, out);
  }
}

// Round 10
// 104.159 us; speedup vs baseline: 21.0788x; 1.1131x over previous
//
#include <hip/hip_runtime.h>
#include <hip/hip_bf16.h>
#include <stdint.h>

// KGEdges round 10 — exp-domain factorization + launch-count reduction.
// Proven semantics (R8/R9 green): out[b,i,j] = sum_d w_out[d]*tanh(head[b,j,d]
// + child[b,i,d]) + mm_i + mm_j ; head = enc@Wh^T + bh, child = enc@Wc^T.
// fp32 in / int32 mask / FP32 OUT. ws >= 9 MiB proven (poison fill shows ~256 MB).
// tanh identity in exp2 domain: sum w*tanh = S + sum(-2w)*rcp(E_h*E_c + 1),
// E = exp2(K*x), K = 2*log2(e). proj stores E directly -> edge inner loop is
// mul+add+rcp+fma (14 issue-cyc/term vs 22 in R9).
// 3 kernels: convert (fp32->bf16 enc/W), proj (MFMA, bit-proven R2 structure),
// edge (product form, per-block w staging + S reduction).

typedef __bf16 bf16_t;
typedef __attribute__((ext_vector_type(8))) __bf16 bf16x8;
typedef __attribute__((ext_vector_type(4))) float f32x4;

#define SL 256
#define ENC 1024
#define NTOT 512
#define N_ENC 2097152   // 8*256*1024
#define N_W 262144      // 256*1024
#define KSCALE 2.8853900817779268f  // 2*log2(e)

__device__ __forceinline__ void async16(void* lds, const void* g) {
  __builtin_amdgcn_global_load_lds(
      (const __attribute__((address_space(1))) uint32_t*)g,
      (__attribute__((address_space(3))) uint32_t*)lds, 16, 0, 0);
}
__device__ __forceinline__ unsigned short f32_to_bf16_rne(float f) {
  uint32_t u = __float_as_uint(f);
  return (unsigned short)((u + 0x7FFFu + ((u >> 16) & 1u)) >> 16);
}

// ---- convert: bf16 copies of enc, Wh, Wc (WB = [Wh;Wc] rows 0..511) ----
__global__ __launch_bounds__(256)
void convert_kernel(const float* __restrict__ enc, const float* __restrict__ Wh,
                    const float* __restrict__ Wc,
                    unsigned short* __restrict__ encB, unsigned short* __restrict__ WB) {
  int gi = (blockIdx.x * 256 + threadIdx.x) * 4;
  const float* src;
  unsigned short* dst;
  int off;
  if (gi < N_ENC) {
    src = enc; off = gi; dst = encB + gi;
  } else if (gi < N_ENC + N_W) {
    src = Wh; off = gi - N_ENC; dst = WB + off;
  } else {
    src = Wc; off = gi - N_ENC - N_W; dst = WB + N_W + off;
  }
  f32x4 v = *(const f32x4*)(src + off);
  ushort4 o;
  o.x = f32_to_bf16_rne(v[0]); o.y = f32_to_bf16_rne(v[1]);
  o.z = f32_to_bf16_rne(v[2]); o.w = f32_to_bf16_rne(v[3]);
  *(ushort4*)dst = o;
}

// ---- proj: hc[s][0:256]=exp2(K*(enc@Wh^T+bh)) [Eh], hc[s][256:512]=exp2(K*enc@Wc^T) [Ec]
// 64x64 tile, BK=32, 4 waves each 2x2 MFMA 16x16x32 bf16. Bit-proven R2 structure;
// only the epilogue changed (exp2 instead of K* linear store).
__global__ __launch_bounds__(256)
void proj_kernel(const unsigned short* __restrict__ A, const unsigned short* __restrict__ WB,
                 const float* __restrict__ bh, float* __restrict__ hc) {
  __shared__ bf16_t As[64 * 32];
  __shared__ bf16_t Bs[64 * 32];
  const int t = threadIdx.x;
  const int wv = t >> 6, lane = t & 63;
  const int m0 = blockIdx.x * 64;   // 32 blocks (2048 rows)
  const int n0 = blockIdx.y * 64;   // 8 blocks (512 cols of [head|child])
  const int srow = t >> 2, schunk = t & 3;
  const int mq = (wv & 1) * 32, nq = (wv >> 1) * 32;
  const int fr = lane & 15, kq = lane >> 4;

  f32x4 acc00 = {0.f, 0.f, 0.f, 0.f};
  f32x4 acc01 = acc00, acc10 = acc00, acc11 = acc00;

  const unsigned short* gA = A + (size_t)(m0 + srow) * ENC + schunk * 8;
  const unsigned short* gB = WB + (size_t)(n0 + srow) * ENC + schunk * 8;

  for (int k0 = 0; k0 < ENC; k0 += 32) {
    __syncthreads();
    async16(&As[wv * 512], gA + k0);  // wave-uniform LDS base + lane*16B
    async16(&Bs[wv * 512], gB + k0);
    __syncthreads();
    bf16x8 a0 = *(const bf16x8*)&As[(mq + fr) * 32 + kq * 8];
    bf16x8 a1 = *(const bf16x8*)&As[(mq + 16 + fr) * 32 + kq * 8];
    bf16x8 b0 = *(const bf16x8*)&Bs[(nq + fr) * 32 + kq * 8];
    bf16x8 b1 = *(const bf16x8*)&Bs[(nq + 16 + fr) * 32 + kq * 8];
    acc00 = __builtin_amdgcn_mfma_f32_16x16x32_bf16(a0, b0, acc00, 0, 0, 0);
    acc01 = __builtin_amdgcn_mfma_f32_16x16x32_bf16(a0, b1, acc01, 0, 0, 0);
    acc10 = __builtin_amdgcn_mfma_f32_16x16x32_bf16(a1, b0, acc10, 0, 0, 0);
    acc11 = __builtin_amdgcn_mfma_f32_16x16x32_bf16(a1, b1, acc11, 0, 0, 0);
  }
  // C/D: col=lane&15, row=(lane>>4)*4+r
  const int colA = n0 + nq + fr;
  const int colB = colA + 16;
  const float biasA = (colA < 256) ? bh[colA] : 0.0f;
  const float biasB = (colB < 256) ? bh[colB] : 0.0f;
#pragma unroll
  for (int r = 0; r < 4; ++r) {
    int row0 = m0 + mq + kq * 4 + r;
    int row1 = row0 + 16;
    hc[(size_t)row0 * NTOT + colA] = __builtin_amdgcn_exp2f(KSCALE * (acc00[r] + biasA));
    hc[(size_t)row0 * NTOT + colB] = __builtin_amdgcn_exp2f(KSCALE * (acc01[r] + biasB));
    hc[(size_t)row1 * NTOT + colA] = __builtin_amdgcn_exp2f(KSCALE * (acc10[r] + biasA));
    hc[(size_t)row1 * NTOT + colB] = __builtin_amdgcn_exp2f(KSCALE * (acc11[r] + biasB));
  }
}

// ---- edge: out[b,i,j] = S + sum_d (-2w[d])*rcp(Eh[j,d]*Ec[i,d]+1) + mm_i + mm_j ----
// 32x32 (i,j) tile; thread 2x2 micro-tile at (+16,+16). head pairs with COLUMN j.
// LDS stride 260 f32: frag reads <=2-way bank aliasing (free per m136).
#define LSTR 260
__global__ __launch_bounds__(256)
void edge_kernel(const float* __restrict__ hc, const float* __restrict__ wout,
                 const int* __restrict__ mask, float* __restrict__ out) {
  __shared__ float ldH[32 * LSTR];
  __shared__ float ldC[32 * LSTR];
  __shared__ float wS[256];
  __shared__ float red[256];
  const int t = threadIdx.x;
  const int b = blockIdx.z;
  const int i0 = blockIdx.y * 32;
  const int j0 = blockIdx.x * 32;
  const int sbase = b * SL;

  float w = wout[t];
  wS[t] = -2.0f * w;   // folded coefficient
  red[t] = w;          // for S = sum w

  for (int u = t; u < 32 * 64; u += 256) {
    int row = u >> 6;
    int c4 = (u & 63) << 2;
    f32x4 hv = *(const f32x4*)&hc[(size_t)(sbase + j0 + row) * NTOT + c4];        // Eh(j)
    f32x4 cv = *(const f32x4*)&hc[(size_t)(sbase + i0 + row) * NTOT + 256 + c4];  // Ec(i)
    *(f32x4*)&ldH[row * LSTR + c4] = hv;
    *(f32x4*)&ldC[row * LSTR + c4] = cv;
  }
  __syncthreads();
  for (int s = 128; s > 0; s >>= 1) {   // block-reduce S (replaces prep kernel)
    if (t < s) red[t] += red[t + s];
    __syncthreads();
  }
  const float S = red[0];

  const int tx = t & 15, ty = t >> 4;
  const float* hp0 = &ldH[tx * LSTR];
  const float* hp1 = &ldH[(tx + 16) * LSTR];
  const float* cp0 = &ldC[ty * LSTR];
  const float* cp1 = &ldC[(ty + 16) * LSTR];
  float a00 = 0.f, a01 = 0.f, a10 = 0.f, a11 = 0.f;

#pragma unroll 8
  for (int d = 0; d < 256; d += 4) {
    f32x4 h0 = *(const f32x4*)&hp0[d];
    f32x4 h1 = *(const f32x4*)&hp1[d];
    f32x4 c0 = *(const f32x4*)&cp0[d];
    f32x4 c1 = *(const f32x4*)&cp1[d];
    f32x4 w4 = *(const f32x4*)&wS[d];  // uniform addr -> LDS broadcast
#pragma unroll
    for (int e = 0; e < 4; ++e) {
      float he0 = h0[e], he1 = h1[e], ce0 = c0[e], ce1 = c1[e], we = w4[e];
      float r00 = __builtin_amdgcn_rcpf(ce0 * he0 + 1.0f);
      float r01 = __builtin_amdgcn_rcpf(ce0 * he1 + 1.0f);
      float r10 = __builtin_amdgcn_rcpf(ce1 * he0 + 1.0f);
      float r11 = __builtin_amdgcn_rcpf(ce1 * he1 + 1.0f);
      a00 = fmaf(we, r00, a00);
      a01 = fmaf(we, r01, a01);
      a10 = fmaf(we, r10, a10);
      a11 = fmaf(we, r11, a11);
    }
  }

  const int gi0 = sbase + i0 + ty, gi1 = gi0 + 16;   // out rows (i, child)
  const int gj0 = j0 + tx, gj1 = gj0 + 16;           // out cols (j, head)
  const float mi0 = (1.0f - (float)mask[gi0]) * -1.0e8f;
  const float mi1 = (1.0f - (float)mask[gi1]) * -1.0e8f;
  const float mj0 = (1.0f - (float)mask[sbase + gj0]) * -1.0e8f;
  const float mj1 = (1.0f - (float)mask[sbase + gj1]) * -1.0e8f;
  out[(size_t)gi0 * SL + gj0] = S + a00 + mi0 + mj0;
  out[(size_t)gi0 * SL + gj1] = S + a01 + mi0 + mj1;
  out[(size_t)gi1 * SL + gj0] = S + a10 + mi1 + mj0;
  out[(size_t)gi1 * SL + gj1] = S + a11 + mi1 + mj1;
}

extern "C" void kernel_launch(void* const* d_in, const int* in_sizes, int n_in,
                              void* d_out, int out_size, void* d_ws, size_t ws_size,
                              hipStream_t stream) {
  (void)in_sizes; (void)n_in; (void)out_size; (void)ws_size;
  const float* enc = (const float*)d_in[0];   // (8,256,1024) fp32
  const int* mask = (const int*)d_in[1];      // (8,256) int32
  const float* Wh = (const float*)d_in[2];    // (256,1024) fp32
  const float* bh = (const float*)d_in[3];    // (256,) fp32
  const float* Wc = (const float*)d_in[4];    // (256,1024) fp32
  const float* wout = (const float*)d_in[5];  // (256,) fp32
  float* out = (float*)d_out;

  char* W = (char*)d_ws;
  float* hc = (float*)W;                                   // 4 MiB (2048x512 f32, exp-domain)
  unsigned short* encB = (unsigned short*)(W + (4 << 20)); // 4 MiB
  unsigned short* WB = (unsigned short*)(W + (8 << 20));   // 1 MiB ([Wh;Wc])

  convert_kernel<<<2560, 256, 0, stream>>>(enc, Wh, Wc, encB, WB);
  proj_kernel<<<dim3(32, 8), 256, 0, stream>>>(encB, WB, bh, hc);
  edge_kernel<<<dim3(8, 8, 8), 256, 0, stream>>>(hc, wout, mask, out);
}